// Round 15
// baseline (268.342 us; speedup 1.0000x reference)
//
#include <hip/hip_runtime.h>

// ---------------------------------------------------------------------------
// Transformer block (RMSNorm -> MHA(causal) -> proj+res -> RMSNorm -> GLU FFN)
// B=2 T=2048 D=1024 H=16 HD=64.  bf16 MFMA 16x16x32, f32 accumulate.
// R15 = R14 + FFN1 rebuilt as schedule-faithful 8-phase 256^2 (vmcnt(6),
// 3-half-tile prefetch depth — fixing R6's 1-phase-lead error).
// ---------------------------------------------------------------------------

typedef __attribute__((ext_vector_type(4))) float f32x4;
typedef __attribute__((ext_vector_type(8))) short short8;

typedef __attribute__((address_space(1))) const void gvoid;
typedef __attribute__((address_space(3))) void lvoid;

static __device__ __forceinline__ void gl_lds16(const void* g, void* l) {
  __builtin_amdgcn_global_load_lds((gvoid*)g, (lvoid*)l, 16, 0, 0);
}

static __device__ __forceinline__ unsigned short f2bf(float f) {
  union { float f; unsigned u; } v; v.f = f;
  unsigned r = v.u + 0x7fffu + ((v.u >> 16) & 1u);   // RNE
  return (unsigned short)(r >> 16);
}
static __device__ __forceinline__ float to_f32(float v) { return v; }
static __device__ __forceinline__ float to_f32(unsigned short v) {
  union { unsigned u; float f; } x; x.u = ((unsigned)v) << 16; return x.f;
}

static __device__ __forceinline__ f32x4 mfma16(short8 a, short8 b, f32x4 c) {
  return __builtin_amdgcn_mfma_f32_16x16x32_bf16(a, b, c, 0, 0, 0);
}

// ---------------------------------------------------------------------------
// Unified prep: weight repacks (f32 -> bf16 B^T) + rmsnorm1, one launch.
// ---------------------------------------------------------------------------
__global__ __launch_bounds__(256) void prep_all(
    const float* __restrict__ wq, const float* __restrict__ wk,
    const float* __restrict__ wv, const float* __restrict__ wproj,
    const float* __restrict__ w1, const float* __restrict__ w2,
    unsigned short* __restrict__ wt_qkv, unsigned short* __restrict__ wpt,
    unsigned short* __restrict__ w1t, unsigned short* __restrict__ w2t,
    const float* __restrict__ x, const float* __restrict__ g1,
    unsigned short* __restrict__ xn)
{
  __shared__ float tile[64][65];
  const int bid = blockIdx.x;
  if (bid >= 4096) {                      // --- rmsnorm1 ---
    int row = bid - 4096;
    int t = threadIdx.x;
    float4 v = ((const float4*)(x + (long)row * 1024))[t];
    float ss = v.x * v.x + v.y * v.y + v.z * v.z + v.w * v.w;
#pragma unroll
    for (int ofs = 32; ofs; ofs >>= 1) ss += __shfl_down(ss, ofs);
    float* red = &tile[0][0];
    if ((t & 63) == 0) red[t >> 6] = ss;
    __syncthreads();
    float sc = rsqrtf((red[0] + red[1] + red[2] + red[3]) * (1.0f / 1024.0f) + 1e-6f);
    float4 gv = ((const float4*)g1)[t];
    ushort4 o4;
    o4.x = f2bf(v.x * sc * gv.x); o4.y = f2bf(v.y * sc * gv.y);
    o4.z = f2bf(v.z * sc * gv.z); o4.w = f2bf(v.w * sc * gv.w);
    ((ushort4*)(xn + (long)row * 1024))[t] = o4;
    return;
  }
  const float* in;
  unsigned short* out;
  int r0, c0, in_ld, out_ld;
  if (bid < 768) {
    int z = bid >> 4, y = bid & 15;
    int head = z & 15, src = z >> 4;
    in = (src == 0 ? wq : src == 1 ? wk : wv) + (long)head * 1024 * 64;
    out = wt_qkv + ((long)src * 1024 + head * 64) * 1024;
    r0 = y * 64; c0 = 0; in_ld = 64; out_ld = 1024;
  } else if (bid < 1024) {
    int f = bid - 768;
    in = wproj; out = wpt;
    c0 = (f & 15) * 64; r0 = (f >> 4) * 64; in_ld = 1024; out_ld = 1024;
  } else if (bid < 3072) {
    int f = bid - 1024;
    in = w1; out = w1t;
    c0 = (f & 127) * 64; r0 = (f >> 7) * 64; in_ld = 8192; out_ld = 1024;
  } else {
    int f = bid - 3072;
    in = w2; out = w2t;
    c0 = (f & 15) * 64; r0 = (f >> 4) * 64; in_ld = 1024; out_ld = 4096;
  }
  int tx = threadIdx.x & 63, ty = threadIdx.x >> 6;
#pragma unroll
  for (int i = ty; i < 64; i += 4)
    tile[i][tx] = in[(long)(r0 + i) * in_ld + (c0 + tx)];
  __syncthreads();
#pragma unroll
  for (int i = ty; i < 64; i += 4)
    out[(long)(c0 + i) * out_ld + (r0 + tx)] = f2bf(tile[tx][i]);
}

// ---------------------------------------------------------------------------
// RMSNorm row kernel (used for rmsnorm2).  D=1024.
// ---------------------------------------------------------------------------
__global__ __launch_bounds__(256) void rmsnorm_k(
    const float* __restrict__ x, const float* __restrict__ g,
    unsigned short* __restrict__ out)
{
  int row = blockIdx.x;
  int t = threadIdx.x;
  float4 v = ((const float4*)(x + (long)row * 1024))[t];
  float ss = v.x * v.x + v.y * v.y + v.z * v.z + v.w * v.w;
#pragma unroll
  for (int ofs = 32; ofs; ofs >>= 1) ss += __shfl_down(ss, ofs);
  __shared__ float red[4];
  if ((t & 63) == 0) red[t >> 6] = ss;
  __syncthreads();
  float sc = rsqrtf((red[0] + red[1] + red[2] + red[3]) * (1.0f / 1024.0f) + 1e-6f);
  float4 gv = ((const float4*)g)[t];
  ushort4 o4;
  o4.x = f2bf(v.x * sc * gv.x); o4.y = f2bf(v.y * sc * gv.y);
  o4.z = f2bf(v.z * sc * gv.z); o4.w = f2bf(v.w * sc * gv.w);
  ((ushort4*)(out + (long)row * 1024))[t] = o4;
}

// ---------------------------------------------------------------------------
// GEMM: C[M][N] = A[M][K] * Bt[N][K]^T, BMx128 tile, 256 threads.
// R3-proven 2-barrier K-loop, parametrized BK. (QKV / proj / FFN2)
// EPI: 0 = bf16, 1 = f32 res+bias, 3 = QKV + fused V^T.
// ---------------------------------------------------------------------------
template <int EPI, int BM, int BK, int WM_, int WN_>
__global__ __launch_bounds__(256, 2) void gemm_bt(
    const unsigned short* __restrict__ A, const unsigned short* __restrict__ Bt,
    unsigned short* __restrict__ outb, float* __restrict__ outf,
    const float* __restrict__ res, const float* __restrict__ bias,
    unsigned short* __restrict__ vtout,
    int K, int lda, int ldbt, int ldout)
{
  constexpr int FM = BM / (16 * WM_);
  constexpr int FN = 128 / (16 * WN_);
  constexpr int KK = BK / 32;
  constexpr int UR = BK / 8;
  constexpr int ARn = BM * UR / 256;
  constexpr int BRn = 128 * UR / 256;
  __shared__ alignas(16) unsigned short Asm_[BM * BK];
  __shared__ alignas(16) unsigned short Bsm_[128 * BK];
  const int tid = threadIdx.x, lane = tid & 63, wave = tid >> 6;
  const int lr = lane & 15, lg = lane >> 4;
  const int wr = wave / WN_, wc = wave % WN_;
  const int m0 = blockIdx.y * BM;

  f32x4 acc[FM][FN];
#pragma unroll
  for (int mi = 0; mi < FM; mi++)
#pragma unroll
    for (int ni = 0; ni < FN; ni++) acc[mi][ni] = f32x4{0.f, 0.f, 0.f, 0.f};

  int rr_[BRn], ru_[BRn];
  long brow[BRn];
#pragma unroll
  for (int i = 0; i < BRn; i++) {
    int U = tid + 256 * i;
    int r = U / UR, u = U % UR;
    rr_[i] = r;
    ru_[i] = ((u & ~7) | ((u ^ r) & 7)) * 8;   // involution source swizzle
    brow[i] = (long)blockIdx.x * 128 + r;
  }

  for (int k0 = 0; k0 < K; k0 += BK) {
#pragma unroll
    for (int i = 0; i < BRn; i++) {
      if (i < ARn)
        gl_lds16(A + (long)(m0 + rr_[i]) * lda + k0 + ru_[i],
                 (char*)Asm_ + (tid + 256 * i) * 16);
      gl_lds16(Bt + brow[i] * ldbt + k0 + ru_[i],
               (char*)Bsm_ + (tid + 256 * i) * 16);
    }
    __syncthreads();

    short8 af[FM][KK], bfr[FN][KK];
#pragma unroll
    for (int mi = 0; mi < FM; mi++) {
      int row = wr * 16 * FM + mi * 16 + lr;
#pragma unroll
      for (int kk = 0; kk < KK; kk++) {
        int u = kk * 4 + lg;
        int off = row * (2 * BK) + ((u & ~7) | ((u ^ (row & 7)) & 7)) * 16;
        af[mi][kk] = *(const short8*)((const char*)Asm_ + off);
      }
    }
#pragma unroll
    for (int ni = 0; ni < FN; ni++) {
      int row = wc * 16 * FN + ni * 16 + lr;
#pragma unroll
      for (int kk = 0; kk < KK; kk++) {
        int u = kk * 4 + lg;
        int off = row * (2 * BK) + ((u & ~7) | ((u ^ (row & 7)) & 7)) * 16;
        bfr[ni][kk] = *(const short8*)((const char*)Bsm_ + off);
      }
    }
#pragma unroll
    for (int kk = 0; kk < KK; kk++)
#pragma unroll
      for (int mi = 0; mi < FM; mi++)
#pragma unroll
        for (int ni = 0; ni < FN; ni++)
          acc[mi][ni] = mfma16(af[mi][kk], bfr[ni][kk], acc[mi][ni]);
    __syncthreads();
  }

  const int rb = m0 + wr * 16 * FM + 4 * lg;
  if constexpr (EPI == 0) {
#pragma unroll
    for (int mi = 0; mi < FM; mi++)
#pragma unroll
      for (int ni = 0; ni < FN; ni++) {
        int col = blockIdx.x * 128 + wc * 16 * FN + ni * 16 + lr;
#pragma unroll
        for (int r = 0; r < 4; r++)
          outb[(long)(rb + mi * 16 + r) * ldout + col] = f2bf(acc[mi][ni][r]);
      }
  } else if constexpr (EPI == 1) {
#pragma unroll
    for (int mi = 0; mi < FM; mi++)
#pragma unroll
      for (int ni = 0; ni < FN; ni++) {
        int col = blockIdx.x * 128 + wc * 16 * FN + ni * 16 + lr;
        float bv = bias[col];
#pragma unroll
        for (int r = 0; r < 4; r++) {
          long idx = (long)(rb + mi * 16 + r) * ldout + col;
          outf[idx] = acc[mi][ni][r] + res[idx] + bv;
        }
      }
  } else {  // EPI == 3: QKV with fused V^T
#pragma unroll
    for (int mi = 0; mi < FM; mi++)
#pragma unroll
      for (int ni = 0; ni < FN; ni++) {
        int col = blockIdx.x * 128 + wc * 16 * FN + ni * 16 + lr;
        int row0 = rb + mi * 16;
        if (col < 2048) {
#pragma unroll
          for (int r = 0; r < 4; r++)
            outb[(long)(row0 + r) * ldout + col] = f2bf(acc[mi][ni][r]);
        } else {
          int c2 = col - 2048;
          int h = c2 >> 6, d = c2 & 63;
          int b = row0 >> 11, t = row0 & 2047;
          ushort4 o4;
          o4.x = f2bf(acc[mi][ni][0]); o4.y = f2bf(acc[mi][ni][1]);
          o4.z = f2bf(acc[mi][ni][2]); o4.w = f2bf(acc[mi][ni][3]);
          *(ushort4*)(vtout + ((long)((b << 4) | h) * 64 + d) * 2048 + t) = o4;
        }
      }
  }
}

// ---------------------------------------------------------------------------
// FFN1+GLU: 8-phase 256x256 schedule (T3+T4+T5), 512 threads (8 waves 2Mx4N),
// BK=64, double-buffered LDS (128 KB), counted vmcnt(6) = 3 half-tiles in
// flight; youngest half of tile u+1 issued 7 phases before its consumer.
// Per K-tile u (buf=u&1):
//   p0: ds af(0-3)+bf0 | stage A1(u+1)->buf^1 | bar lgkm Q1 bar
//   p1: ds bf1         |                      | bar lgkm Q2 bar
//   p2: ds af(4-7)     | stage B0(u+2)->buf   | bar lgkm Q3 bar
//   p3: stage B1(u+2),A0(u+2)->buf | Q4 | vmcnt(6) bar
// WAR: B-region of buf free after p1, A-region after p2 (phase barriers).
// GLU: 256 B-rows = per-wc 32 a-rows + 32 b-rows of same output cols.
// ---------------------------------------------------------------------------
__global__ __launch_bounds__(512, 1) void gemm8_glu(
    const unsigned short* __restrict__ A, const unsigned short* __restrict__ Bt,
    unsigned short* __restrict__ outb, const float* __restrict__ bias,
    int K, int lda, int ldbt, int ldout)
{
  __shared__ alignas(16) unsigned short Asm_[2][2][128 * 64];  // [buf][half]
  __shared__ alignas(16) unsigned short Bsm_[2][2][128 * 64];
  const int tid = threadIdx.x, lane = tid & 63, wave = tid >> 6;
  const int lr = lane & 15, lg = lane >> 4;
  const int wr = wave >> 2, wc = wave & 3;
  const int m0 = blockIdx.y * 256;
  const int bx = blockIdx.x;

  f32x4 acc[8][4];
#pragma unroll
  for (int mi = 0; mi < 8; mi++)
#pragma unroll
    for (int ni = 0; ni < 4; ni++) acc[mi][ni] = f32x4{0.f, 0.f, 0.f, 0.f};

  auto stageA = [&](int buf, int h, int kt) {
#pragma unroll
    for (int i = 0; i < 2; i++) {
      int U = tid + 512 * i;
      int r = U >> 3, s = (U ^ r) & 7;
      gl_lds16(A + (long)(m0 + h * 128 + r) * lda + kt * 64 + s * 8,
               (char*)&Asm_[buf][h][0] + U * 16);
    }
  };
  auto stageB = [&](int buf, int h, int kt) {
#pragma unroll
    for (int i = 0; i < 2; i++) {
      int U = tid + 512 * i;
      int r = U >> 3, s = (U ^ r) & 7;
      int row = h * 128 + r;                       // 0..255 panel row
      int w = row >> 6, o = row & 63;
      long br = (o < 32) ? (long)(bx * 128 + w * 32 + o)
                         : (long)4096 + bx * 128 + w * 32 + (o - 32);
      gl_lds16(Bt + br * ldbt + kt * 64 + s * 8,
               (char*)&Bsm_[buf][h][0] + U * 16);
    }
  };
  auto lda8 = [&](int buf, int mi, int kk) -> short8 {
    int rl = mi * 16 + lr;
    int u = kk * 4 + lg;
    return *(const short8*)((const char*)&Asm_[buf][wr][0] + rl * 128 +
                            ((u ^ (rl & 7)) * 16));
  };
  auto ldb8 = [&](int buf, int ni, int kk) -> short8 {
    int row = wc * 64 + ni * 16 + lr;
    int h = row >> 7, rl = row & 127;
    int u = kk * 4 + lg;
    return *(const short8*)((const char*)&Bsm_[buf][h][0] + rl * 128 +
                            ((u ^ (rl & 7)) * 16));
  };

  short8 af[4][2], bf0[2][2], bf1[2][2];
#define QUAD(BF, MI0, NI0)                                                   \
  do {                                                                       \
    __builtin_amdgcn_s_setprio(1);                                           \
    _Pragma("unroll") for (int kk_ = 0; kk_ < 2; kk_++)                      \
    _Pragma("unroll") for (int mi_ = 0; mi_ < 4; mi_++)                      \
    _Pragma("unroll") for (int ni_ = 0; ni_ < 2; ni_++)                      \
      acc[(MI0) + mi_][(NI0) + ni_] =                                        \
          mfma16(af[mi_][kk_], BF[ni_][kk_], acc[(MI0) + mi_][(NI0) + ni_]); \
    __builtin_amdgcn_s_setprio(0);                                           \
  } while (0)

  // prologue: tiles 0 fully + tile 1 {B0,B1,A0} = 7 halves (14 vmem/thread)
  stageB(0, 0, 0); stageB(0, 1, 0); stageA(0, 0, 0); stageA(0, 1, 0);
  stageB(1, 0, 1); stageB(1, 1, 1); stageA(1, 0, 1);
  asm volatile("s_waitcnt vmcnt(6)" ::: "memory");   // tile0 resident
  __builtin_amdgcn_s_barrier();

  const int NT = K / 64;
  for (int u = 0; u < NT; ++u) {
    const int buf = u & 1;
    // ---- p0 ----
#pragma unroll
    for (int mi = 0; mi < 4; mi++)
#pragma unroll
      for (int kk = 0; kk < 2; kk++) af[mi][kk] = lda8(buf, mi, kk);
#pragma unroll
    for (int ni = 0; ni < 2; ni++)
#pragma unroll
      for (int kk = 0; kk < 2; kk++) bf0[ni][kk] = ldb8(buf, ni, kk);
    if (u + 1 < NT) stageA(buf ^ 1, 1, u + 1);
    __builtin_amdgcn_s_barrier();
    asm volatile("s_waitcnt lgkmcnt(0)" ::: "memory");
    QUAD(bf0, 0, 0);
    __builtin_amdgcn_s_barrier();
    // ---- p1 ----
#pragma unroll
    for (int ni = 0; ni < 2; ni++)
#pragma unroll
      for (int kk = 0; kk < 2; kk++) bf1[ni][kk] = ldb8(buf, ni + 2, kk);
    __builtin_amdgcn_s_barrier();
    asm volatile("s_waitcnt lgkmcnt(0)" ::: "memory");
    QUAD(bf1, 0, 2);
    __builtin_amdgcn_s_barrier();
    // ---- p2 ----
#pragma unroll
    for (int mi = 0; mi < 4; mi++)
#pragma unroll
      for (int kk = 0; kk < 2; kk++) af[mi][kk] = lda8(buf, mi + 4, kk);
    if (u + 2 < NT) stageB(buf, 0, u + 2);
    __builtin_amdgcn_s_barrier();
    asm volatile("s_waitcnt lgkmcnt(0)" ::: "memory");
    QUAD(bf1, 4, 2);
    __builtin_amdgcn_s_barrier();
    // ---- p3 ----
    if (u + 2 < NT) { stageB(buf, 1, u + 2); stageA(buf, 0, u + 2); }
    QUAD(bf0, 4, 0);
    if (u == NT - 2)     asm volatile("s_waitcnt vmcnt(0)" ::: "memory");
    else if (u < NT - 2) asm volatile("s_waitcnt vmcnt(6)" ::: "memory");
    __builtin_amdgcn_s_barrier();
  }
#undef QUAD

  // GLU epilogue: acc[mi][ni] (a) paired with acc[mi][ni+2] (b)
#pragma unroll
  for (int mi = 0; mi < 8; mi++)
#pragma unroll
    for (int ni = 0; ni < 2; ni++) {
      int col = bx * 128 + wc * 32 + ni * 16 + lr;
      float ba = bias[col], bb = bias[4096 + col];
#pragma unroll
      for (int r = 0; r < 4; r++) {
        int row = m0 + wr * 128 + mi * 16 + 4 * lg + r;
        float a = acc[mi][ni][r] + ba;
        float b = acc[mi][ni + 2][r] + bb;
        float s = 1.0f / (1.0f + __expf(-b));
        outb[(long)row * ldout + col] = f2bf(a * s);
      }
    }
}

// ---------------------------------------------------------------------------
// Flash attention, causal, LOAD-BALANCED (exact R11/R14 version).
// ---------------------------------------------------------------------------
__global__ __launch_bounds__(256, 2) void attn_k(
    const unsigned short* __restrict__ qkv, const unsigned short* __restrict__ vt,
    unsigned short* __restrict__ o)
{
  __shared__ alignas(16) unsigned short Ksm[2 * 128 * 64];   // [kv=128][d=64]
  __shared__ alignas(16) unsigned short Vsm[2 * 64 * 128];   // [d=64][kv=128]
  __shared__ alignas(16) unsigned short Psm[4][16 * 128];    // per-wave [q=16][kv=128]
  const int tid = threadIdx.x, lane = tid & 63, wave = tid >> 6;
  const int lr = lane & 15, lg = lane >> 4;
  const int bh = blockIdx.y, b = bh >> 4, h = bh & 15;
  const int ia = blockIdx.x;                       // 0..15
  const int tA0 = ia * 64, tB0 = (31 - ia) * 64;
  const int nchA = (ia + 2) >> 1, nchB = (33 - ia) >> 1;   // chunks of 128 kv
  const float NEGINF = -__builtin_inff();

  short8 qfA[2], qfB[2];
  {
    const unsigned short* qp =
        qkv + (long)(b * 2048 + tA0 + wave * 16 + lr) * 3072 + h * 64 + lg * 8;
    qfA[0] = *(const short8*)qp;  qfA[1] = *(const short8*)(qp + 32);
    qp = qkv + (long)(b * 2048 + tB0 + wave * 16 + lr) * 3072 + h * 64 + lg * 8;
    qfB[0] = *(const short8*)qp;  qfB[1] = *(const short8*)(qp + 32);
  }
  f32x4 oA[4], oB[4];
#pragma unroll
  for (int n = 0; n < 4; n++) { oA[n] = f32x4{0,0,0,0}; oB[n] = f32x4{0,0,0,0}; }
  float mA = NEGINF, lA = 0.f, mB = NEGINF, lB = 0.f;

  const long kbase = (long)(b * 2048) * 3072 + 1024 + h * 64;
  const long vbase = (long)bh * 64 * 2048;

  auto stage = [&](int buf, int c) {
    const int s0 = c * 128;
#pragma unroll
    for (int i = 0; i < 4; i++) {
      int U = tid + 256 * i;
      int kr = U >> 3, ku = (U ^ kr) & 7;                 // K: 128 rows x 8 units
      gl_lds16(qkv + kbase + (long)(s0 + kr) * 3072 + ku * 8,
               (char*)Ksm + (buf * 1024 + wave * 64 + 256 * i) * 16);
      int vr = U >> 4, vu = (U & 8) | ((U ^ vr) & 7);     // V: 64 rows x 16 units
      gl_lds16(vt + vbase + (long)vr * 2048 + s0 + vu * 8,
               (char*)Vsm + (buf * 1024 + wave * 64 + 256 * i) * 16);
    }
  };

  char* pb = (char*)&Psm[wave][0];

  auto qk = [&](const short8* qf, f32x4* s, const char* kb) {
#pragma unroll
    for (int n = 0; n < 8; n++) s[n] = f32x4{0.f, 0.f, 0.f, 0.f};
#pragma unroll
    for (int n = 0; n < 8; n++) {
      int row = n * 16 + lr;
#pragma unroll
      for (int kk = 0; kk < 2; kk++) {
        int off = row * 128 + (((kk * 4 + lg) ^ row) & 7) * 16;
        short8 kf = *(const short8*)(kb + off);
        s[n] = mfma16(kf, qf[kk], s[n]);
      }
    }
  };

  auto smpv = [&](f32x4* s, f32x4* o_acc, float& m, float& l,
                  const char* vb, int s0, int qg, bool diag) {
#pragma unroll
    for (int n = 0; n < 8; n++)
#pragma unroll
      for (int r = 0; r < 4; r++) {
        float v = s[n][r] * 0.125f;
        if (diag && (s0 + n * 16 + 4 * lg + r > qg)) v = NEGINF;
        s[n][r] = v;
      }
    float t[8];
#pragma unroll
    for (int n = 0; n < 8; n++)
      t[n] = fmaxf(fmaxf(s[n][0], s[n][1]), fmaxf(s[n][2], s[n][3]));
    float mx = fmaxf(fmaxf(fmaxf(t[0], t[1]), fmaxf(t[2], t[3])),
                     fmaxf(fmaxf(t[4], t[5]), fmaxf(t[6], t[7])));
    mx = fmaxf(mx, __shfl_xor(mx, 16));
    mx = fmaxf(mx, __shfl_xor(mx, 32));
    if (!__all(mx <= m + 8.0f)) {
      float mn = fmaxf(m, mx);
      float alpha = __expf(m - mn);
      m = mn;
      l *= alpha;
#pragma unroll
      for (int r = 0; r < 4; r++) {
        float ar = __shfl(alpha, 4 * lg + r);
#pragma unroll
        for (int n = 0; n < 4; n++) o_acc[n][r] *= ar;
      }
    }
    float sum = 0.f;
#pragma unroll
    for (int n = 0; n < 8; n++)
#pragma unroll
      for (int r = 0; r < 4; r++) {
        float p = __expf(s[n][r] - m);
        s[n][r] = p;
        sum += p;
      }
    sum += __shfl_xor(sum, 16);
    sum += __shfl_xor(sum, 32);
    l += sum;
#pragma unroll
    for (int n = 0; n < 8; n++) {
      unsigned lo = (unsigned)f2bf(s[n][0]) | ((unsigned)f2bf(s[n][1]) << 16);
      unsigned hi = (unsigned)f2bf(s[n][2]) | ((unsigned)f2bf(s[n][3]) << 16);
      int u = 2 * n + (lg >> 1);
      int su = (u & 8) | ((u ^ lr) & 7);
      *(uint2*)(pb + lr * 256 + su * 16 + 8 * (lg & 1)) = uint2{lo, hi};
    }
    asm volatile("s_waitcnt lgkmcnt(0)" ::: "memory");
    __builtin_amdgcn_sched_barrier(0);
    short8 pa[4];
#pragma unroll
    for (int ks = 0; ks < 4; ks++) {
      int u = 4 * ks + lg;
      int su = (u & 8) | ((u ^ lr) & 7);
      pa[ks] = *(const short8*)(pb + lr * 256 + su * 16);
    }
    __builtin_amdgcn_s_setprio(1);
#pragma unroll
    for (int n = 0; n < 4; n++) {
      int row = n * 16 + lr;
#pragma unroll
      for (int ks = 0; ks < 4; ks++) {
        int u = 4 * ks + lg;
        int su = (u & 8) | ((u ^ row) & 7);
        short8 vf = *(const short8*)(vb + row * 256 + su * 16);
        o_acc[n] = mfma16(pa[ks], vf, o_acc[n]);
      }
    }
    __builtin_amdgcn_s_setprio(0);
  };

  stage(0, 0);
  __syncthreads();

  const int qgA = tA0 + wave * 16 + lr, qgB = tB0 + wave * 16 + lr;
  for (int c = 0; c < nchB; c++) {
    if (c + 1 < nchB) stage((c + 1) & 1, c + 1);
    const char* kb = (const char*)Ksm + (c & 1) * 16384;
    const char* vb = (const char*)Vsm + (c & 1) * 16384;
    const int s0 = c * 128;
    const bool doA = (c < nchA);
    f32x4 sA[8], sB[8];
    __builtin_amdgcn_s_setprio(1);
    if (doA) qk(qfA, sA, kb);
    qk(qfB, sB, kb);
    __builtin_amdgcn_s_setprio(0);
    if (doA) smpv(sA, oA, mA, lA, vb, s0, qgA, c == nchA - 1);
    smpv(sB, oB, mB, lB, vb, s0, qgB, c == nchB - 1);
    __syncthreads();
  }

  auto finish = [&](const f32x4* o_acc, float l, int t0) {
#pragma unroll
    for (int r = 0; r < 4; r++) {
      float inv = 1.0f / __shfl(l, 4 * lg + r);
      int trow = t0 + wave * 16 + 4 * lg + r;
#pragma unroll
      for (int n = 0; n < 4; n++)
        o[(long)(b * 2048 + trow) * 1024 + h * 64 + n * 16 + lr] =
            f2bf(o_acc[n][r] * inv);
    }
  };
  finish(oA, lA, tA0);
  finish(oB, lB, tB0);
}

// ---------------------------------------------------------------------------
extern "C" void kernel_launch(void* const* d_in, const int* in_sizes, int n_in,
                              void* d_out, int out_size, void* d_ws, size_t ws_size,
                              hipStream_t stream) {
  const float* x     = (const float*)d_in[0];
  const float* wq    = (const float*)d_in[1];
  const float* wk    = (const float*)d_in[2];
  const float* wv    = (const float*)d_in[3];
  const float* wproj = (const float*)d_in[4];
  const float* bproj = (const float*)d_in[5];
  const float* w1    = (const float*)d_in[6];
  const float* b1    = (const float*)d_in[7];
  const float* w2    = (const float*)d_in[8];
  const float* b2    = (const float*)d_in[9];
  const float* g1    = (const float*)d_in[10];
  const float* g2    = (const float*)d_in[11];
  (void)in_sizes; (void)n_in; (void)out_size; (void)ws_size;

  char* ws = (char*)d_ws;
  unsigned short* wt_qkv = (unsigned short*)(ws);                    // 6 MB [3072][1024]
  unsigned short* wpt    = (unsigned short*)(ws + (6ul << 20));      // 2 MB [1024][1024]
  unsigned short* w1t    = (unsigned short*)(ws + (8ul << 20));      // 16 MB [8192][1024]
  unsigned short* w2t    = (unsigned short*)(ws + (24ul << 20));     // 8 MB [1024][4096]
  unsigned short* xn     = (unsigned short*)(ws + (32ul << 20));     // 8 MB [4096][1024]
  unsigned short* qkv    = (unsigned short*)(ws + (40ul << 20));     // 24 MB [4096][3072] (v region unused)
  unsigned short* vt     = (unsigned short*)(ws + (64ul << 20));     // 8 MB [32][64][2048]
  unsigned short* glu    = (unsigned short*)(ws + (40ul << 20));     // 32 MB alias (qkv+vt dead)
  unsigned short* obuf   = (unsigned short*)(ws + (72ul << 20));     // 8 MB [4096][1024]
  float*          x1     = (float*)(ws + (80ul << 20));              // 16 MB [4096][1024]
  float* outf = (float*)d_out;

  // --- weight repacks + rmsnorm1, one launch ---
  prep_all<<<8192, 256, 0, stream>>>(wq, wk, wv, wproj, w1, w2,
                                     wt_qkv, wpt, w1t, w2t, x, g1, xn);

  // --- QKV GEMM with fused V^T write (EPI=3) ---
  gemm_bt<3, 128, 64, 2, 2><<<dim3(24, 32), 256, 0, stream>>>(
      xn, wt_qkv, qkv, nullptr, nullptr, nullptr, vt, 1024, 1024, 1024, 3072);

  // --- attention (tile-paired, balanced; R11-proven Vsm staging) ---
  attn_k<<<dim3(16, 32), 256, 0, stream>>>(qkv, vt, obuf);

  // --- proj + residual + bias -> x1 (f32): 64x128 tiles, BK=128 ---
  gemm_bt<1, 64, 128, 2, 2><<<dim3(8, 64), 256, 0, stream>>>(
      obuf, wpt, nullptr, x1, x, bproj, nullptr, 1024, 1024, 1024, 1024);

  // --- rmsnorm 2 ---
  rmsnorm_k<<<4096, 256, 0, stream>>>(x1, g2, xn);

  // --- FFN1 + GLU -> glu bf16 [4096][4096]: 8-phase 256^2, vmcnt(6) ---
  gemm8_glu<<<dim3(32, 16), 512, 0, stream>>>(
      xn, w1t, glu, b1, 1024, 1024, 1024, 4096);

  // --- FFN2 + residual + bias -> d_out (f32): 64x128 tiles, BK=128 ---
  gemm_bt<1, 64, 128, 2, 2><<<dim3(8, 64), 256, 0, stream>>>(
      glu, w2t, nullptr, outf, x1, b2, nullptr, 4096, 4096, 4096, 1024);
}

// Round 16
// 259.514 us; speedup vs baseline: 1.0340x; 1.0340x over previous
//
#include <hip/hip_runtime.h>

// ---------------------------------------------------------------------------
// Transformer block (RMSNorm -> MHA(causal) -> proj+res -> RMSNorm -> GLU FFN)
// B=2 T=2048 D=1024 H=16 HD=64.  bf16 MFMA 16x16x32, f32 accumulate.
// R16 = exact R14 configuration (verified best: 260.4 us).
// Closed directions (measured): 8-phase FFN1 (R6/R7/R15: 77 us vs 68.9),
// XCD swizzle (R13: 5x FETCH), V-unstaging (R12: +90 us), depth-2 vmcnt on
// 2-phase (R4: regressed), setprio on lockstep GEMM (R5: -12%).
// ---------------------------------------------------------------------------

typedef __attribute__((ext_vector_type(4))) float f32x4;
typedef __attribute__((ext_vector_type(8))) short short8;

typedef __attribute__((address_space(1))) const void gvoid;
typedef __attribute__((address_space(3))) void lvoid;

static __device__ __forceinline__ void gl_lds16(const void* g, void* l) {
  __builtin_amdgcn_global_load_lds((gvoid*)g, (lvoid*)l, 16, 0, 0);
}

static __device__ __forceinline__ unsigned short f2bf(float f) {
  union { float f; unsigned u; } v; v.f = f;
  unsigned r = v.u + 0x7fffu + ((v.u >> 16) & 1u);   // RNE
  return (unsigned short)(r >> 16);
}
static __device__ __forceinline__ float to_f32(float v) { return v; }
static __device__ __forceinline__ float to_f32(unsigned short v) {
  union { unsigned u; float f; } x; x.u = ((unsigned)v) << 16; return x.f;
}

static __device__ __forceinline__ f32x4 mfma16(short8 a, short8 b, f32x4 c) {
  return __builtin_amdgcn_mfma_f32_16x16x32_bf16(a, b, c, 0, 0, 0);
}

// ---------------------------------------------------------------------------
// Unified prep: weight repacks (f32 -> bf16 B^T) + rmsnorm1, one launch.
// ---------------------------------------------------------------------------
__global__ __launch_bounds__(256) void prep_all(
    const float* __restrict__ wq, const float* __restrict__ wk,
    const float* __restrict__ wv, const float* __restrict__ wproj,
    const float* __restrict__ w1, const float* __restrict__ w2,
    unsigned short* __restrict__ wt_qkv, unsigned short* __restrict__ wpt,
    unsigned short* __restrict__ w1t, unsigned short* __restrict__ w2t,
    const float* __restrict__ x, const float* __restrict__ g1,
    unsigned short* __restrict__ xn)
{
  __shared__ float tile[64][65];
  const int bid = blockIdx.x;
  if (bid >= 4096) {                      // --- rmsnorm1 ---
    int row = bid - 4096;
    int t = threadIdx.x;
    float4 v = ((const float4*)(x + (long)row * 1024))[t];
    float ss = v.x * v.x + v.y * v.y + v.z * v.z + v.w * v.w;
#pragma unroll
    for (int ofs = 32; ofs; ofs >>= 1) ss += __shfl_down(ss, ofs);
    float* red = &tile[0][0];
    if ((t & 63) == 0) red[t >> 6] = ss;
    __syncthreads();
    float sc = rsqrtf((red[0] + red[1] + red[2] + red[3]) * (1.0f / 1024.0f) + 1e-6f);
    float4 gv = ((const float4*)g1)[t];
    ushort4 o4;
    o4.x = f2bf(v.x * sc * gv.x); o4.y = f2bf(v.y * sc * gv.y);
    o4.z = f2bf(v.z * sc * gv.z); o4.w = f2bf(v.w * sc * gv.w);
    ((ushort4*)(xn + (long)row * 1024))[t] = o4;
    return;
  }
  const float* in;
  unsigned short* out;
  int r0, c0, in_ld, out_ld;
  if (bid < 768) {
    int z = bid >> 4, y = bid & 15;
    int head = z & 15, src = z >> 4;
    in = (src == 0 ? wq : src == 1 ? wk : wv) + (long)head * 1024 * 64;
    out = wt_qkv + ((long)src * 1024 + head * 64) * 1024;
    r0 = y * 64; c0 = 0; in_ld = 64; out_ld = 1024;
  } else if (bid < 1024) {
    int f = bid - 768;
    in = wproj; out = wpt;
    c0 = (f & 15) * 64; r0 = (f >> 4) * 64; in_ld = 1024; out_ld = 1024;
  } else if (bid < 3072) {
    int f = bid - 1024;
    in = w1; out = w1t;
    c0 = (f & 127) * 64; r0 = (f >> 7) * 64; in_ld = 8192; out_ld = 1024;
  } else {
    int f = bid - 3072;
    in = w2; out = w2t;
    c0 = (f & 15) * 64; r0 = (f >> 4) * 64; in_ld = 1024; out_ld = 4096;
  }
  int tx = threadIdx.x & 63, ty = threadIdx.x >> 6;
#pragma unroll
  for (int i = ty; i < 64; i += 4)
    tile[i][tx] = in[(long)(r0 + i) * in_ld + (c0 + tx)];
  __syncthreads();
#pragma unroll
  for (int i = ty; i < 64; i += 4)
    out[(long)(c0 + i) * out_ld + (r0 + tx)] = f2bf(tile[tx][i]);
}

// ---------------------------------------------------------------------------
// RMSNorm row kernel (used for rmsnorm2).  D=1024.
// ---------------------------------------------------------------------------
__global__ __launch_bounds__(256) void rmsnorm_k(
    const float* __restrict__ x, const float* __restrict__ g,
    unsigned short* __restrict__ out)
{
  int row = blockIdx.x;
  int t = threadIdx.x;
  float4 v = ((const float4*)(x + (long)row * 1024))[t];
  float ss = v.x * v.x + v.y * v.y + v.z * v.z + v.w * v.w;
#pragma unroll
  for (int ofs = 32; ofs; ofs >>= 1) ss += __shfl_down(ss, ofs);
  __shared__ float red[4];
  if ((t & 63) == 0) red[t >> 6] = ss;
  __syncthreads();
  float sc = rsqrtf((red[0] + red[1] + red[2] + red[3]) * (1.0f / 1024.0f) + 1e-6f);
  float4 gv = ((const float4*)g)[t];
  ushort4 o4;
  o4.x = f2bf(v.x * sc * gv.x); o4.y = f2bf(v.y * sc * gv.y);
  o4.z = f2bf(v.z * sc * gv.z); o4.w = f2bf(v.w * sc * gv.w);
  ((ushort4*)(out + (long)row * 1024))[t] = o4;
}

// ---------------------------------------------------------------------------
// GEMM: C[M][N] = A[M][K] * Bt[N][K]^T, BMx128 tile, 256 threads.
// R3-proven 2-barrier K-loop, parametrized BK. Default blockIdx order.
// GLUB: a/b B-rows interleaved per wave span (GLU pairing at any WN_).
// EPI: 0 = bf16, 1 = f32 res+bias, 2 = GLU pair->bf16, 3 = QKV + fused V^T.
// ---------------------------------------------------------------------------
template <int EPI, int BM, int BK, int WM_, int WN_, bool GLUB>
__global__ __launch_bounds__(256, 2) void gemm_bt(
    const unsigned short* __restrict__ A, const unsigned short* __restrict__ Bt,
    unsigned short* __restrict__ outb, float* __restrict__ outf,
    const float* __restrict__ res, const float* __restrict__ bias,
    unsigned short* __restrict__ vtout,
    int K, int lda, int ldbt, int ldout)
{
  constexpr int FM = BM / (16 * WM_);
  constexpr int FN = 128 / (16 * WN_);
  constexpr int KK = BK / 32;
  constexpr int UR = BK / 8;
  constexpr int ARn = BM * UR / 256;
  constexpr int BRn = 128 * UR / 256;
  constexpr int SPAN = 16 * FN;
  constexpr int HALF = SPAN / 2;
  __shared__ alignas(16) unsigned short Asm_[BM * BK];
  __shared__ alignas(16) unsigned short Bsm_[128 * BK];
  const int tid = threadIdx.x, lane = tid & 63, wave = tid >> 6;
  const int lr = lane & 15, lg = lane >> 4;
  const int wr = wave / WN_, wc = wave % WN_;
  const int m0 = blockIdx.y * BM;

  f32x4 acc[FM][FN];
#pragma unroll
  for (int mi = 0; mi < FM; mi++)
#pragma unroll
    for (int ni = 0; ni < FN; ni++) acc[mi][ni] = f32x4{0.f, 0.f, 0.f, 0.f};

  int rr_[BRn], ru_[BRn];
  long brow[BRn];
#pragma unroll
  for (int i = 0; i < BRn; i++) {
    int U = tid + 256 * i;
    int r = U / UR, u = U % UR;
    rr_[i] = r;
    ru_[i] = ((u & ~7) | ((u ^ r) & 7)) * 8;   // involution source swizzle
    if (GLUB) {
      int w = r / SPAN, o = r % SPAN;
      brow[i] = (long)((o >= HALF) ? 4096 : 0) + blockIdx.x * 64 +
                w * HALF + (o % HALF);
    } else {
      brow[i] = (long)blockIdx.x * 128 + r;
    }
  }

  for (int k0 = 0; k0 < K; k0 += BK) {
#pragma unroll
    for (int i = 0; i < BRn; i++) {
      if (i < ARn)
        gl_lds16(A + (long)(m0 + rr_[i]) * lda + k0 + ru_[i],
                 (char*)Asm_ + (tid + 256 * i) * 16);
      gl_lds16(Bt + brow[i] * ldbt + k0 + ru_[i],
               (char*)Bsm_ + (tid + 256 * i) * 16);
    }
    __syncthreads();

    short8 af[FM][KK], bfr[FN][KK];
#pragma unroll
    for (int mi = 0; mi < FM; mi++) {
      int row = wr * 16 * FM + mi * 16 + lr;
#pragma unroll
      for (int kk = 0; kk < KK; kk++) {
        int u = kk * 4 + lg;
        int off = row * (2 * BK) + ((u & ~7) | ((u ^ (row & 7)) & 7)) * 16;
        af[mi][kk] = *(const short8*)((const char*)Asm_ + off);
      }
    }
#pragma unroll
    for (int ni = 0; ni < FN; ni++) {
      int row = wc * 16 * FN + ni * 16 + lr;
#pragma unroll
      for (int kk = 0; kk < KK; kk++) {
        int u = kk * 4 + lg;
        int off = row * (2 * BK) + ((u & ~7) | ((u ^ (row & 7)) & 7)) * 16;
        bfr[ni][kk] = *(const short8*)((const char*)Bsm_ + off);
      }
    }
#pragma unroll
    for (int kk = 0; kk < KK; kk++)
#pragma unroll
      for (int mi = 0; mi < FM; mi++)
#pragma unroll
        for (int ni = 0; ni < FN; ni++)
          acc[mi][ni] = mfma16(af[mi][kk], bfr[ni][kk], acc[mi][ni]);
    __syncthreads();
  }

  const int rb = m0 + wr * 16 * FM + 4 * lg;
  if constexpr (EPI == 0) {
#pragma unroll
    for (int mi = 0; mi < FM; mi++)
#pragma unroll
      for (int ni = 0; ni < FN; ni++) {
        int col = blockIdx.x * 128 + wc * 16 * FN + ni * 16 + lr;
#pragma unroll
        for (int r = 0; r < 4; r++)
          outb[(long)(rb + mi * 16 + r) * ldout + col] = f2bf(acc[mi][ni][r]);
      }
  } else if constexpr (EPI == 1) {
#pragma unroll
    for (int mi = 0; mi < FM; mi++)
#pragma unroll
      for (int ni = 0; ni < FN; ni++) {
        int col = blockIdx.x * 128 + wc * 16 * FN + ni * 16 + lr;
        float bv = bias[col];
#pragma unroll
        for (int r = 0; r < 4; r++) {
          long idx = (long)(rb + mi * 16 + r) * ldout + col;
          outf[idx] = acc[mi][ni][r] + res[idx] + bv;
        }
      }
  } else if constexpr (EPI == 2) {  // GLU
#pragma unroll
    for (int mi = 0; mi < FM; mi++)
#pragma unroll
      for (int ni = 0; ni < FN / 2; ni++) {
        int col = blockIdx.x * 64 + wc * HALF + ni * 16 + lr;
        float ba = bias[col], bb2 = bias[4096 + col];
#pragma unroll
        for (int r = 0; r < 4; r++) {
          float a = acc[mi][ni][r] + ba;
          float b = acc[mi][ni + FN / 2][r] + bb2;
          float s = 1.0f / (1.0f + __expf(-b));
          outb[(long)(rb + mi * 16 + r) * ldout + col] = f2bf(a * s);
        }
      }
  } else {  // EPI == 3: QKV with fused V^T
#pragma unroll
    for (int mi = 0; mi < FM; mi++)
#pragma unroll
      for (int ni = 0; ni < FN; ni++) {
        int col = blockIdx.x * 128 + wc * 16 * FN + ni * 16 + lr;
        int row0 = rb + mi * 16;
        if (col < 2048) {
#pragma unroll
          for (int r = 0; r < 4; r++)
            outb[(long)(row0 + r) * ldout + col] = f2bf(acc[mi][ni][r]);
        } else {
          int c2 = col - 2048;
          int h = c2 >> 6, d = c2 & 63;
          int b = row0 >> 11, t = row0 & 2047;
          ushort4 o4;
          o4.x = f2bf(acc[mi][ni][0]); o4.y = f2bf(acc[mi][ni][1]);
          o4.z = f2bf(acc[mi][ni][2]); o4.w = f2bf(acc[mi][ni][3]);
          *(ushort4*)(vtout + ((long)((b << 4) | h) * 64 + d) * 2048 + t) = o4;
        }
      }
  }
}

// ---------------------------------------------------------------------------
// Flash attention, causal, LOAD-BALANCED (R11-proven configuration).
// ---------------------------------------------------------------------------
__global__ __launch_bounds__(256, 2) void attn_k(
    const unsigned short* __restrict__ qkv, const unsigned short* __restrict__ vt,
    unsigned short* __restrict__ o)
{
  __shared__ alignas(16) unsigned short Ksm[2 * 128 * 64];   // [kv=128][d=64]
  __shared__ alignas(16) unsigned short Vsm[2 * 64 * 128];   // [d=64][kv=128]
  __shared__ alignas(16) unsigned short Psm[4][16 * 128];    // per-wave [q=16][kv=128]
  const int tid = threadIdx.x, lane = tid & 63, wave = tid >> 6;
  const int lr = lane & 15, lg = lane >> 4;
  const int bh = blockIdx.y, b = bh >> 4, h = bh & 15;
  const int ia = blockIdx.x;                       // 0..15
  const int tA0 = ia * 64, tB0 = (31 - ia) * 64;
  const int nchA = (ia + 2) >> 1, nchB = (33 - ia) >> 1;   // chunks of 128 kv
  const float NEGINF = -__builtin_inff();

  short8 qfA[2], qfB[2];
  {
    const unsigned short* qp =
        qkv + (long)(b * 2048 + tA0 + wave * 16 + lr) * 3072 + h * 64 + lg * 8;
    qfA[0] = *(const short8*)qp;  qfA[1] = *(const short8*)(qp + 32);
    qp = qkv + (long)(b * 2048 + tB0 + wave * 16 + lr) * 3072 + h * 64 + lg * 8;
    qfB[0] = *(const short8*)qp;  qfB[1] = *(const short8*)(qp + 32);
  }
  f32x4 oA[4], oB[4];
#pragma unroll
  for (int n = 0; n < 4; n++) { oA[n] = f32x4{0,0,0,0}; oB[n] = f32x4{0,0,0,0}; }
  float mA = NEGINF, lA = 0.f, mB = NEGINF, lB = 0.f;

  const long kbase = (long)(b * 2048) * 3072 + 1024 + h * 64;
  const long vbase = (long)bh * 64 * 2048;

  auto stage = [&](int buf, int c) {
    const int s0 = c * 128;
#pragma unroll
    for (int i = 0; i < 4; i++) {
      int U = tid + 256 * i;
      int kr = U >> 3, ku = (U ^ kr) & 7;                 // K: 128 rows x 8 units
      gl_lds16(qkv + kbase + (long)(s0 + kr) * 3072 + ku * 8,
               (char*)Ksm + (buf * 1024 + wave * 64 + 256 * i) * 16);
      int vr = U >> 4, vu = (U & 8) | ((U ^ vr) & 7);     // V: 64 rows x 16 units
      gl_lds16(vt + vbase + (long)vr * 2048 + s0 + vu * 8,
               (char*)Vsm + (buf * 1024 + wave * 64 + 256 * i) * 16);
    }
  };

  char* pb = (char*)&Psm[wave][0];

  auto qk = [&](const short8* qf, f32x4* s, const char* kb) {
#pragma unroll
    for (int n = 0; n < 8; n++) s[n] = f32x4{0.f, 0.f, 0.f, 0.f};
#pragma unroll
    for (int n = 0; n < 8; n++) {
      int row = n * 16 + lr;
#pragma unroll
      for (int kk = 0; kk < 2; kk++) {
        int off = row * 128 + (((kk * 4 + lg) ^ row) & 7) * 16;
        short8 kf = *(const short8*)(kb + off);
        s[n] = mfma16(kf, qf[kk], s[n]);
      }
    }
  };

  auto smpv = [&](f32x4* s, f32x4* o_acc, float& m, float& l,
                  const char* vb, int s0, int qg, bool diag) {
#pragma unroll
    for (int n = 0; n < 8; n++)
#pragma unroll
      for (int r = 0; r < 4; r++) {
        float v = s[n][r] * 0.125f;
        if (diag && (s0 + n * 16 + 4 * lg + r > qg)) v = NEGINF;
        s[n][r] = v;
      }
    float t[8];
#pragma unroll
    for (int n = 0; n < 8; n++)
      t[n] = fmaxf(fmaxf(s[n][0], s[n][1]), fmaxf(s[n][2], s[n][3]));
    float mx = fmaxf(fmaxf(fmaxf(t[0], t[1]), fmaxf(t[2], t[3])),
                     fmaxf(fmaxf(t[4], t[5]), fmaxf(t[6], t[7])));
    mx = fmaxf(mx, __shfl_xor(mx, 16));
    mx = fmaxf(mx, __shfl_xor(mx, 32));
    if (!__all(mx <= m + 8.0f)) {
      float mn = fmaxf(m, mx);
      float alpha = __expf(m - mn);
      m = mn;
      l *= alpha;
#pragma unroll
      for (int r = 0; r < 4; r++) {
        float ar = __shfl(alpha, 4 * lg + r);
#pragma unroll
        for (int n = 0; n < 4; n++) o_acc[n][r] *= ar;
      }
    }
    float sum = 0.f;
#pragma unroll
    for (int n = 0; n < 8; n++)
#pragma unroll
      for (int r = 0; r < 4; r++) {
        float p = __expf(s[n][r] - m);
        s[n][r] = p;
        sum += p;
      }
    sum += __shfl_xor(sum, 16);
    sum += __shfl_xor(sum, 32);
    l += sum;
#pragma unroll
    for (int n = 0; n < 8; n++) {
      unsigned lo = (unsigned)f2bf(s[n][0]) | ((unsigned)f2bf(s[n][1]) << 16);
      unsigned hi = (unsigned)f2bf(s[n][2]) | ((unsigned)f2bf(s[n][3]) << 16);
      int u = 2 * n + (lg >> 1);
      int su = (u & 8) | ((u ^ lr) & 7);
      *(uint2*)(pb + lr * 256 + su * 16 + 8 * (lg & 1)) = uint2{lo, hi};
    }
    asm volatile("s_waitcnt lgkmcnt(0)" ::: "memory");
    __builtin_amdgcn_sched_barrier(0);
    short8 pa[4];
#pragma unroll
    for (int ks = 0; ks < 4; ks++) {
      int u = 4 * ks + lg;
      int su = (u & 8) | ((u ^ lr) & 7);
      pa[ks] = *(const short8*)(pb + lr * 256 + su * 16);
    }
    __builtin_amdgcn_s_setprio(1);
#pragma unroll
    for (int n = 0; n < 4; n++) {
      int row = n * 16 + lr;
#pragma unroll
      for (int ks = 0; ks < 4; ks++) {
        int u = 4 * ks + lg;
        int su = (u & 8) | ((u ^ row) & 7);
        short8 vf = *(const short8*)(vb + row * 256 + su * 16);
        o_acc[n] = mfma16(pa[ks], vf, o_acc[n]);
      }
    }
    __builtin_amdgcn_s_setprio(0);
  };

  stage(0, 0);
  __syncthreads();

  const int qgA = tA0 + wave * 16 + lr, qgB = tB0 + wave * 16 + lr;
  for (int c = 0; c < nchB; c++) {
    if (c + 1 < nchB) stage((c + 1) & 1, c + 1);
    const char* kb = (const char*)Ksm + (c & 1) * 16384;
    const char* vb = (const char*)Vsm + (c & 1) * 16384;
    const int s0 = c * 128;
    const bool doA = (c < nchA);
    f32x4 sA[8], sB[8];
    __builtin_amdgcn_s_setprio(1);
    if (doA) qk(qfA, sA, kb);
    qk(qfB, sB, kb);
    __builtin_amdgcn_s_setprio(0);
    if (doA) smpv(sA, oA, mA, lA, vb, s0, qgA, c == nchA - 1);
    smpv(sB, oB, mB, lB, vb, s0, qgB, c == nchB - 1);
    __syncthreads();
  }

  auto finish = [&](const f32x4* o_acc, float l, int t0) {
#pragma unroll
    for (int r = 0; r < 4; r++) {
      float inv = 1.0f / __shfl(l, 4 * lg + r);
      int trow = t0 + wave * 16 + 4 * lg + r;
#pragma unroll
      for (int n = 0; n < 4; n++)
        o[(long)(b * 2048 + trow) * 1024 + h * 64 + n * 16 + lr] =
            f2bf(o_acc[n][r] * inv);
    }
  };
  finish(oA, lA, tA0);
  finish(oB, lB, tB0);
}

// ---------------------------------------------------------------------------
extern "C" void kernel_launch(void* const* d_in, const int* in_sizes, int n_in,
                              void* d_out, int out_size, void* d_ws, size_t ws_size,
                              hipStream_t stream) {
  const float* x     = (const float*)d_in[0];
  const float* wq    = (const float*)d_in[1];
  const float* wk    = (const float*)d_in[2];
  const float* wv    = (const float*)d_in[3];
  const float* wproj = (const float*)d_in[4];
  const float* bproj = (const float*)d_in[5];
  const float* w1    = (const float*)d_in[6];
  const float* b1    = (const float*)d_in[7];
  const float* w2    = (const float*)d_in[8];
  const float* b2    = (const float*)d_in[9];
  const float* g1    = (const float*)d_in[10];
  const float* g2    = (const float*)d_in[11];
  (void)in_sizes; (void)n_in; (void)out_size; (void)ws_size;

  char* ws = (char*)d_ws;
  unsigned short* wt_qkv = (unsigned short*)(ws);                    // 6 MB [3072][1024]
  unsigned short* wpt    = (unsigned short*)(ws + (6ul << 20));      // 2 MB [1024][1024]
  unsigned short* w1t    = (unsigned short*)(ws + (8ul << 20));      // 16 MB [8192][1024]
  unsigned short* w2t    = (unsigned short*)(ws + (24ul << 20));     // 8 MB [1024][4096]
  unsigned short* xn     = (unsigned short*)(ws + (32ul << 20));     // 8 MB [4096][1024]
  unsigned short* qkv    = (unsigned short*)(ws + (40ul << 20));     // 24 MB [4096][3072] (v region unused)
  unsigned short* vt     = (unsigned short*)(ws + (64ul << 20));     // 8 MB [32][64][2048]
  unsigned short* glu    = (unsigned short*)(ws + (40ul << 20));     // 32 MB alias (qkv+vt dead)
  unsigned short* obuf   = (unsigned short*)(ws + (72ul << 20));     // 8 MB [4096][1024]
  float*          x1     = (float*)(ws + (80ul << 20));              // 16 MB [4096][1024]
  float* outf = (float*)d_out;

  // --- weight repacks + rmsnorm1, one launch ---
  prep_all<<<8192, 256, 0, stream>>>(wq, wk, wv, wproj, w1, w2,
                                     wt_qkv, wpt, w1t, w2t, x, g1, xn);

  // --- QKV GEMM with fused V^T write (EPI=3) ---
  gemm_bt<3, 128, 64, 2, 2, false><<<dim3(24, 32), 256, 0, stream>>>(
      xn, wt_qkv, qkv, nullptr, nullptr, nullptr, vt, 1024, 1024, 1024, 3072);

  // --- attention (tile-paired, balanced; R11-proven Vsm staging) ---
  attn_k<<<dim3(16, 32), 256, 0, stream>>>(qkv, vt, obuf);

  // --- proj + residual + bias -> x1 (f32): 64x128 tiles, BK=128 ---
  gemm_bt<1, 64, 128, 2, 2, false><<<dim3(8, 64), 256, 0, stream>>>(
      obuf, wpt, nullptr, x1, x, bproj, nullptr, 1024, 1024, 1024, 1024);

  // --- rmsnorm 2 ---
  rmsnorm_k<<<4096, 256, 0, stream>>>(x1, g2, xn);

  // --- FFN1 + GLU -> glu bf16 [4096][4096]: WM2/WN2 (16 ds_read/K-step) ---
  gemm_bt<2, 128, 64, 2, 2, true><<<dim3(64, 32), 256, 0, stream>>>(
      xn, w1t, glu, nullptr, nullptr, b1, nullptr, 1024, 1024, 1024, 4096);

  // --- FFN2 + residual + bias -> d_out (f32): 64x128 tiles, BK=128 ---
  gemm_bt<1, 64, 128, 2, 2, false><<<dim3(8, 64), 256, 0, stream>>>(
      glu, w2t, nullptr, outf, x1, b2, nullptr, 4096, 4096, 4096, 1024);
}